// Round 12
// baseline (253.914 us; speedup 1.0000x reference)
//
#include <hip/hip_runtime.h>
#include <math.h>

#define D_DIM 1024
#define H_DIM 4096
#define R_DIM 64
#define S_SP  4
#define NTOK  8192
#define CHUNK 1024   // H/S

typedef __attribute__((ext_vector_type(8))) float f8;

// async global->LDS DMA: wave-uniform LDS base + lane*16 dest, per-lane src
__device__ __forceinline__ void gload_lds16(const float* g, float* l) {
  __builtin_amdgcn_global_load_lds(
      (const __attribute__((address_space(1))) unsigned int*)(unsigned long long)(uintptr_t)g,
      (__attribute__((address_space(3))) unsigned int*)(uintptr_t)l,
      16, 0, 0);
}

// force a pointer into SGPRs (wave-uniform) -> scalar s_load path
__device__ __forceinline__ const float* uniform_ptr(const float* p) {
  unsigned long long u = (unsigned long long)p;
  unsigned int lo = __builtin_amdgcn_readfirstlane((unsigned int)u);
  unsigned int hi = __builtin_amdgcn_readfirstlane((unsigned int)(u >> 32));
  return (const float*)(((unsigned long long)hi << 32) | lo);
}

// ---- K_A: fused {W2 transpose | Wc2 transpose | ctrl GEMM} ----
#define C_TOK 16
__global__ __launch_bounds__(256, 4) void k_fusedA(const float* __restrict__ W2,
                                                   float* __restrict__ W2T,
                                                   const float* __restrict__ Wc2,
                                                   float* __restrict__ Wc2T,
                                                   const float* __restrict__ x,
                                                   const float* __restrict__ Wc1,
                                                   const float* __restrict__ bc1,
                                                   float* __restrict__ chT_g) {
  __shared__ float smem[64 * 68 + 64 * 20];
  int bid = blockIdx.x;
  const int tid = threadIdx.x;
  if (bid < 1088) {
    float (*tile)[65] = (float (*)[65])smem;
    const float* in; float* out; int R, C, cb, rb;
    if (bid < 1024) {
      in = W2; out = W2T; R = D_DIM; C = H_DIM;
      cb = (bid & 63) * 64; rb = (bid >> 6) * 64;
    } else {
      bid -= 1024;
      in = Wc2; out = Wc2T; R = H_DIM; C = R_DIM;
      cb = 0; rb = bid * 64;
    }
    const int tx = tid & 63, ty = tid >> 6;
#pragma unroll
    for (int r = 0; r < 16; ++r) {
      const int rr = ty * 16 + r;
      tile[tx][rr] = in[(size_t)(rb + rr) * C + cb + tx];
    }
    __syncthreads();
#pragma unroll
    for (int r = 0; r < 16; ++r) {
      const int cc = ty * 16 + r;
      out[(size_t)(cb + cc) * R + rb + tx] = tile[cc][tx];
    }
    return;
  }
  float (*wT)[68] = (float (*)[68])smem;               // [k][r]
  float (*xT)[20] = (float (*)[20])(smem + 64 * 68);   // [k][tok]
  const int tok0 = (bid - 1088) * C_TOK;
  const int lrow = tid >> 4;
  const int lk4  = (tid & 15) * 4;
  const int th = tid & 15;
  const int r4 = (tid >> 4) * 4;
  float acc[4] = {0.f, 0.f, 0.f, 0.f};
#pragma unroll 1
  for (int k0 = 0; k0 < D_DIM; k0 += 64) {
    __syncthreads();
    {
      const float4 v = *(const float4*)(x + (size_t)(tok0 + lrow) * D_DIM + k0 + lk4);
      xT[lk4 + 0][lrow] = v.x; xT[lk4 + 1][lrow] = v.y;
      xT[lk4 + 2][lrow] = v.z; xT[lk4 + 3][lrow] = v.w;
    }
#pragma unroll
    for (int rep = 0; rep < 4; ++rep) {
      const int row = lrow + rep * 16;
      const float4 v = *(const float4*)(Wc1 + (size_t)row * D_DIM + k0 + lk4);
      wT[lk4 + 0][row] = v.x; wT[lk4 + 1][row] = v.y;
      wT[lk4 + 2][row] = v.z; wT[lk4 + 3][row] = v.w;
    }
    __syncthreads();
#pragma unroll 8
    for (int k = 0; k < 64; ++k) {
      const float xv = xT[k][th];
      const float4 wv = *(const float4*)&wT[k][r4];
      acc[0] = fmaf(xv, wv.x, acc[0]);
      acc[1] = fmaf(xv, wv.y, acc[1]);
      acc[2] = fmaf(xv, wv.z, acc[2]);
      acc[3] = fmaf(xv, wv.w, acc[3]);
    }
  }
#pragma unroll
  for (int j = 0; j < 4; ++j) {
    const float v = acc[j] + bc1[r4 + j];
    chT_g[(size_t)(r4 + j) * NTOK + tok0 + th] = v > 0.f ? v : 0.f;
  }
}

// ---- K2a: 32tok x 256h block; ch via SGPR s_load (no LDS), Wc2T in LDS ----
// wave = 8 tok x 256 h; thread = 8 tok x 4 h (acc 32 VGPR).
// Per k: 1 ds_read_b128 + 1 s_load_dwordx8 + 32 FMA -> FMA-bound.
#define G_TOK 32
#define G_HB  256
__global__ __launch_bounds__(256, 2) void k_gate_a(const float* __restrict__ chT_g,
                                                   const float* __restrict__ Wc2T,
                                                   const float* __restrict__ bc2,
                                                   const float* __restrict__ gumbel,
                                                   float2* __restrict__ part) {
  __shared__ float wT[64 * 256];   // 64 KB
  const int tid = threadIdx.x;
  const int tok0 = blockIdx.x * G_TOK;
  const int hb = blockIdx.y;           // 0..3
  const int s  = blockIdx.z;           // 0..3
  const int h0 = hb * G_HB;
  const int w    = tid >> 6;           // wave 0..3
  const int lane = tid & 63;
  const int lane4 = lane * 4;

  // stage Wc2T tile [64 k][256 h]: wave w owns k rows [w*16, w*16+16)
#pragma unroll
  for (int j = 0; j < 16; ++j) {
    const int k = w * 16 + j;
    gload_lds16(Wc2T + (size_t)k * H_DIM + s * CHUNK + h0 + lane4, &wT[k * 256]);
  }

  // wave-uniform scalar base for this wave's 8 tokens
  const float* cb = uniform_ptr(chT_g + tok0 + w * 8);

  float acc[8][4];
#pragma unroll
  for (int i = 0; i < 8; ++i)
#pragma unroll
    for (int j = 0; j < 4; ++j) acc[i][j] = 0.f;

  __syncthreads();
#pragma unroll 4
  for (int k = 0; k < 64; ++k) {
    const f8 c = *(const f8*)(cb + (size_t)k * NTOK);   // s_load_dwordx8
    const float4 wv = *(const float4*)&wT[k * 256 + lane4];
#pragma unroll
    for (int i = 0; i < 8; ++i) {
      acc[i][0] = fmaf(c[i], wv.x, acc[i][0]);
      acc[i][1] = fmaf(c[i], wv.y, acc[i][1]);
      acc[i][2] = fmaf(c[i], wv.z, acc[i][2]);
      acc[i][3] = fmaf(c[i], wv.w, acc[i][3]);
    }
  }

  // epilogue: + bias + gumbel; full-wave argmax per token (idx ascending w/ lane)
  const float4 b = *(const float4*)(bc2 + s * CHUNK + h0 + lane4);
#pragma unroll
  for (int i = 0; i < 8; ++i) {
    const int tok = tok0 + w * 8 + i;
    const float4 g = *(const float4*)(gumbel + ((size_t)tok * S_SP + s) * CHUNK + h0 + lane4);
    float bv = -INFINITY; int bi = 0;
    {
      const float v0 = acc[i][0] + b.x + g.x;
      const float v1 = acc[i][1] + b.y + g.y;
      const float v2 = acc[i][2] + b.z + g.z;
      const float v3 = acc[i][3] + b.w + g.w;
      bv = v0; bi = lane4;
      if (v1 > bv) { bv = v1; bi = lane4 + 1; }
      if (v2 > bv) { bv = v2; bi = lane4 + 2; }
      if (v3 > bv) { bv = v3; bi = lane4 + 3; }
    }
#pragma unroll
    for (int o = 32; o > 0; o >>= 1) {
      const float ov = __shfl_down(bv, o);
      const int   oi = __shfl_down(bi, o);
      if (ov > bv || (ov == bv && oi < bi)) { bv = ov; bi = oi; }
    }
    if (lane == 0)
      part[((size_t)tok * S_SP + s) * 4 + hb] = make_float2(bv, __int_as_float(h0 + bi));
  }
}

// ------- K3: wave-per-token sparse FFN; folds the partial-argmax reduce ---
__global__ __launch_bounds__(256) void k_ffn(const float* __restrict__ x,
                                             const float* __restrict__ W1,
                                             const float* __restrict__ b1,
                                             const float* __restrict__ W2T,
                                             const float* __restrict__ b2,
                                             const float2* __restrict__ part,
                                             float* __restrict__ out) {
  const int tid  = threadIdx.x;
  const int lane = tid & 63;
  const int wv   = tid >> 6;
  const int token = blockIdx.x * 4 + wv;
  // final argmax: lanes 0..15 reduce 4 partials per s (width-4 groups)
  float bv = -INFINITY; int bi = 0;
  {
    const int ss = (lane >> 2) & 3;
    const int q  = lane & 3;
    if (lane < 16) {
      const float2 p = part[((size_t)token * S_SP + ss) * 4 + q];
      bv = p.x; bi = __float_as_int(p.y);
    }
#pragma unroll
    for (int o = 2; o > 0; o >>= 1) {
      const float ov = __shfl_down(bv, o, 4);
      const int   oi = __shfl_down(bi, o, 4);
      if (ov > bv || (ov == bv && oi < bi)) { bv = ov; bi = oi; }
    }
  }
  int h[4];
#pragma unroll
  for (int s2 = 0; s2 < 4; ++s2)
    h[s2] = s2 * CHUNK + __shfl(bi, s2 * 4);

  const int d0 = lane * 16;
  const float* xp = x + (size_t)token * D_DIM + d0;
  const float4 x0 = *(const float4*)(xp + 0);
  const float4 x1 = *(const float4*)(xp + 4);
  const float4 x2 = *(const float4*)(xp + 8);
  const float4 x3 = *(const float4*)(xp + 12);
  float p[4];
#pragma unroll
  for (int s2 = 0; s2 < 4; ++s2) {
    const float* wr = W1 + (size_t)h[s2] * D_DIM + d0;
    const float4 a0 = *(const float4*)(wr + 0);
    const float4 a1 = *(const float4*)(wr + 4);
    const float4 a2 = *(const float4*)(wr + 8);
    const float4 a3 = *(const float4*)(wr + 12);
    float v = 0.f;
    v = fmaf(x0.x, a0.x, v); v = fmaf(x0.y, a0.y, v);
    v = fmaf(x0.z, a0.z, v); v = fmaf(x0.w, a0.w, v);
    v = fmaf(x1.x, a1.x, v); v = fmaf(x1.y, a1.y, v);
    v = fmaf(x1.z, a1.z, v); v = fmaf(x1.w, a1.w, v);
    v = fmaf(x2.x, a2.x, v); v = fmaf(x2.y, a2.y, v);
    v = fmaf(x2.z, a2.z, v); v = fmaf(x2.w, a2.w, v);
    v = fmaf(x3.x, a3.x, v); v = fmaf(x3.y, a3.y, v);
    v = fmaf(x3.z, a3.z, v); v = fmaf(x3.w, a3.w, v);
    p[s2] = v;
  }
#pragma unroll
  for (int s2 = 0; s2 < 4; ++s2) {
#pragma unroll
    for (int o = 1; o < 64; o <<= 1) p[s2] += __shfl_xor(p[s2], o);
  }
  float hvv[4];
#pragma unroll
  for (int s2 = 0; s2 < 4; ++s2) {
    const float v = p[s2] + b1[h[s2]];
    hvv[s2] = v > 0.f ? v : 0.f;
  }
  float4 o0 = *(const float4*)(b2 + d0 + 0);
  float4 o1 = *(const float4*)(b2 + d0 + 4);
  float4 o2 = *(const float4*)(b2 + d0 + 8);
  float4 o3 = *(const float4*)(b2 + d0 + 12);
#pragma unroll
  for (int s2 = 0; s2 < 4; ++s2) {
    const float* wr = W2T + (size_t)h[s2] * D_DIM + d0;
    const float4 a0 = *(const float4*)(wr + 0);
    const float4 a1 = *(const float4*)(wr + 4);
    const float4 a2 = *(const float4*)(wr + 8);
    const float4 a3 = *(const float4*)(wr + 12);
    const float g = hvv[s2];
    o0.x = fmaf(g, a0.x, o0.x); o0.y = fmaf(g, a0.y, o0.y);
    o0.z = fmaf(g, a0.z, o0.z); o0.w = fmaf(g, a0.w, o0.w);
    o1.x = fmaf(g, a1.x, o1.x); o1.y = fmaf(g, a1.y, o1.y);
    o1.z = fmaf(g, a1.z, o1.z); o1.w = fmaf(g, a1.w, o1.w);
    o2.x = fmaf(g, a2.x, o2.x); o2.y = fmaf(g, a2.y, o2.y);
    o2.z = fmaf(g, a2.z, o2.z); o2.w = fmaf(g, a2.w, o2.w);
    o3.x = fmaf(g, a3.x, o3.x); o3.y = fmaf(g, a3.y, o3.y);
    o3.z = fmaf(g, a3.z, o3.z); o3.w = fmaf(g, a3.w, o3.w);
  }
  float* op = out + (size_t)token * D_DIM + d0;
  *(float4*)(op + 0)  = o0;
  *(float4*)(op + 4)  = o1;
  *(float4*)(op + 8)  = o2;
  *(float4*)(op + 12) = o3;
}

extern "C" void kernel_launch(void* const* d_in, const int* in_sizes, int n_in,
                              void* d_out, int out_size, void* d_ws, size_t ws_size,
                              hipStream_t stream) {
  const float* x      = (const float*)d_in[0];
  const float* W1     = (const float*)d_in[1];
  const float* b1     = (const float*)d_in[2];
  const float* W2     = (const float*)d_in[3];
  const float* b2     = (const float*)d_in[4];
  const float* Wc1    = (const float*)d_in[5];
  const float* bc1    = (const float*)d_in[6];
  const float* Wc2    = (const float*)d_in[7];
  const float* bc2    = (const float*)d_in[8];
  const float* gumbel = (const float*)d_in[9];
  float* out = (float*)d_out;

  char* ws = (char*)d_ws;
  float*  W2T   = (float*)ws;                                   // 16.78 MB
  float*  chT_g = (float*)(ws + 16777216);                      //  2.10 MB
  float2* part  = (float2*)(ws + 16777216 + 2097152);           //  1.05 MB
  float*  Wc2T  = (float*)(ws + 16777216 + 2097152 + 2097152);  //  1.05 MB

  hipLaunchKernelGGL(k_fusedA, dim3(1088 + NTOK / C_TOK), dim3(256), 0, stream,
                     W2, W2T, Wc2, Wc2T, x, Wc1, bc1, chT_g);
  hipLaunchKernelGGL(k_gate_a, dim3(NTOK / G_TOK, CHUNK / G_HB, S_SP), dim3(256), 0, stream,
                     chT_g, Wc2T, bc2, gumbel, part);
  hipLaunchKernelGGL(k_ffn, dim3(NTOK / 4), dim3(256), 0, stream,
                     x, W1, b1, W2T, b2, part, out);
}

// Round 13
// 233.953 us; speedup vs baseline: 1.0853x; 1.0853x over previous
//
#include <hip/hip_runtime.h>
#include <math.h>

#define D_DIM 1024
#define H_DIM 4096
#define R_DIM 64
#define S_SP  4
#define NTOK  8192
#define CHUNK 1024   // H/S

// async global->LDS DMA: wave-uniform LDS base + lane*16 dest, per-lane src
__device__ __forceinline__ void gload_lds16(const float* g, float* l) {
  __builtin_amdgcn_global_load_lds(
      (const __attribute__((address_space(1))) unsigned int*)(unsigned long long)(uintptr_t)g,
      (__attribute__((address_space(3))) unsigned int*)(uintptr_t)l,
      16, 0, 0);
}

// ---- K_A: fused {W2 transpose | Wc2 transpose | ctrl GEMM} ----
#define C_TOK 16
__global__ __launch_bounds__(256, 4) void k_fusedA(const float* __restrict__ W2,
                                                   float* __restrict__ W2T,
                                                   const float* __restrict__ Wc2,
                                                   float* __restrict__ Wc2T,
                                                   const float* __restrict__ x,
                                                   const float* __restrict__ Wc1,
                                                   const float* __restrict__ bc1,
                                                   float* __restrict__ chT_g) {
  __shared__ float smem[64 * 68 + 64 * 20];
  int bid = blockIdx.x;
  const int tid = threadIdx.x;
  if (bid < 1088) {
    float (*tile)[65] = (float (*)[65])smem;
    const float* in; float* out; int R, C, cb, rb;
    if (bid < 1024) {
      in = W2; out = W2T; R = D_DIM; C = H_DIM;
      cb = (bid & 63) * 64; rb = (bid >> 6) * 64;
    } else {
      bid -= 1024;
      in = Wc2; out = Wc2T; R = H_DIM; C = R_DIM;
      cb = 0; rb = bid * 64;
    }
    const int tx = tid & 63, ty = tid >> 6;
#pragma unroll
    for (int r = 0; r < 16; ++r) {
      const int rr = ty * 16 + r;
      tile[tx][rr] = in[(size_t)(rb + rr) * C + cb + tx];
    }
    __syncthreads();
#pragma unroll
    for (int r = 0; r < 16; ++r) {
      const int cc = ty * 16 + r;
      out[(size_t)(cb + cc) * R + rb + tx] = tile[cc][tx];
    }
    return;
  }
  float (*wT)[68] = (float (*)[68])smem;               // [k][r]
  float (*xT)[20] = (float (*)[20])(smem + 64 * 68);   // [k][tok]
  const int tok0 = (bid - 1088) * C_TOK;
  const int lrow = tid >> 4;
  const int lk4  = (tid & 15) * 4;
  const int th = tid & 15;
  const int r4 = (tid >> 4) * 4;
  float acc[4] = {0.f, 0.f, 0.f, 0.f};
#pragma unroll 1
  for (int k0 = 0; k0 < D_DIM; k0 += 64) {
    __syncthreads();
    {
      const float4 v = *(const float4*)(x + (size_t)(tok0 + lrow) * D_DIM + k0 + lk4);
      xT[lk4 + 0][lrow] = v.x; xT[lk4 + 1][lrow] = v.y;
      xT[lk4 + 2][lrow] = v.z; xT[lk4 + 3][lrow] = v.w;
    }
#pragma unroll
    for (int rep = 0; rep < 4; ++rep) {
      const int row = lrow + rep * 16;
      const float4 v = *(const float4*)(Wc1 + (size_t)row * D_DIM + k0 + lk4);
      wT[lk4 + 0][row] = v.x; wT[lk4 + 1][row] = v.y;
      wT[lk4 + 2][row] = v.z; wT[lk4 + 3][row] = v.w;
    }
    __syncthreads();
#pragma unroll 8
    for (int k = 0; k < 64; ++k) {
      const float xv = xT[k][th];
      const float4 wv = *(const float4*)&wT[k][r4];
      acc[0] = fmaf(xv, wv.x, acc[0]);
      acc[1] = fmaf(xv, wv.y, acc[1]);
      acc[2] = fmaf(xv, wv.z, acc[2]);
      acc[3] = fmaf(xv, wv.w, acc[3]);
    }
  }
#pragma unroll
  for (int j = 0; j < 4; ++j) {
    const float v = acc[j] + bc1[r4 + j];
    chT_g[(size_t)(r4 + j) * NTOK + tok0 + th] = v > 0.f ? v : 0.f;
  }
}

// ---- K2a: 128tok x 128h tile, K=64 in two 32-phases, DMA-staged LDS ----
// Exact R8 structure + gumbel/bias prefetched into registers BEFORE the
// GEMM (addresses depend only on block/tid; 2x2048-cy compute covers HBM).
#define G_TOK 128
#define G_HB  128
__global__ __launch_bounds__(256, 4) void k_gate_a(const float* __restrict__ chT_g,
                                                   const float* __restrict__ Wc2T,
                                                   const float* __restrict__ bc2,
                                                   const float* __restrict__ gumbel,
                                                   float2* __restrict__ part) {
  __shared__ float chT[32 * 128];
  __shared__ float wT[32 * 128];
  const int tid = threadIdx.x;
  const int tok0 = blockIdx.x * G_TOK;
  const int hb = blockIdx.y;           // 0..7
  const int s  = blockIdx.z;           // 0..3
  const int h0 = hb * G_HB;
  const int w    = tid >> 6;           // wave 0..3
  const int lane = tid & 63;
  const int lsub = lane >> 5;          // 0/1
  const int lcol = (lane & 31) * 4;
  const int th  = tid & 15;
  const int tt8 = (tid >> 4) * 8;
  const int th4 = th * 4;

  // ---- prefetch gumbel (8 tokens) + bias before the GEMM ----
  float4 gA[8], gB[8];
#pragma unroll
  for (int i = 0; i < 8; ++i) {
    const int tok = tok0 + tt8 + i;
    const float* gp = gumbel + ((size_t)tok * S_SP + s) * CHUNK + h0;
    gA[i] = *(const float4*)(gp + th4);
    gB[i] = *(const float4*)(gp + 64 + th4);
  }
  const float4 b0 = *(const float4*)(bc2 + s * CHUNK + h0 + th4);
  const float4 b1 = *(const float4*)(bc2 + s * CHUNK + h0 + 64 + th4);

  float acc[8][8];
#pragma unroll
  for (int i = 0; i < 8; ++i)
#pragma unroll
    for (int j = 0; j < 8; ++j) acc[i][j] = 0.f;

#pragma unroll 1
  for (int p = 0; p < 2; ++p) {
    __syncthreads();
#pragma unroll
    for (int j = 0; j < 4; ++j) {
      const int krow = 8 * w + 2 * j + lsub;
      gload_lds16(chT_g + (size_t)(p * 32 + krow) * NTOK + tok0 + lcol,
                  &chT[(8 * w + 2 * j) * 128]);
      gload_lds16(Wc2T + (size_t)(p * 32 + krow) * H_DIM + s * CHUNK + h0 + lcol,
                  &wT[(8 * w + 2 * j) * 128]);
    }
    __syncthreads();
#pragma unroll 8
    for (int k = 0; k < 32; ++k) {
      const float4 c0 = *(const float4*)&chT[k * 128 + tt8];
      const float4 c1 = *(const float4*)&chT[k * 128 + tt8 + 4];
      const float4 w0 = *(const float4*)&wT[k * 128 + th4];
      const float4 w1 = *(const float4*)&wT[k * 128 + 64 + th4];
      const float ca[8] = {c0.x, c0.y, c0.z, c0.w, c1.x, c1.y, c1.z, c1.w};
      const float wa[8] = {w0.x, w0.y, w0.z, w0.w, w1.x, w1.y, w1.z, w1.w};
#pragma unroll
      for (int i = 0; i < 8; ++i)
#pragma unroll
        for (int j = 0; j < 8; ++j) acc[i][j] = fmaf(ca[i], wa[j], acc[i][j]);
    }
  }

  // epilogue: + bias + gumbel (already in regs), per-token partial argmax
  const float ba[8] = {b0.x, b0.y, b0.z, b0.w, b1.x, b1.y, b1.z, b1.w};
#pragma unroll
  for (int i = 0; i < 8; ++i) {
    const int tok = tok0 + tt8 + i;
    const float ga[8] = {gA[i].x, gA[i].y, gA[i].z, gA[i].w,
                         gB[i].x, gB[i].y, gB[i].z, gB[i].w};
    float bv = -INFINITY; int bi = 0;
#pragma unroll
    for (int j = 0; j < 8; ++j) {
      const int hl = (j < 4) ? (th4 + j) : (64 + th4 + j - 4);
      const float val = acc[i][j] + ba[j] + ga[j];
      if (val > bv) { bv = val; bi = hl; }   // ascending hl within thread
    }
#pragma unroll
    for (int o = 8; o > 0; o >>= 1) {
      const float ov = __shfl_down(bv, o, 16);
      const int   oi = __shfl_down(bi, o, 16);
      if (ov > bv || (ov == bv && oi < bi)) { bv = ov; bi = oi; }
    }
    if (th == 0)
      part[((size_t)tok * S_SP + s) * 8 + hb] = make_float2(bv, __int_as_float(h0 + bi));
  }
}

// ------- K3: wave-per-token sparse FFN; folds the partial-argmax reduce ---
__global__ __launch_bounds__(256) void k_ffn(const float* __restrict__ x,
                                             const float* __restrict__ W1,
                                             const float* __restrict__ b1,
                                             const float* __restrict__ W2T,
                                             const float* __restrict__ b2,
                                             const float2* __restrict__ part,
                                             float* __restrict__ out) {
  const int tid  = threadIdx.x;
  const int lane = tid & 63;
  const int wv   = tid >> 6;
  const int token = blockIdx.x * 4 + wv;
  // final argmax: lanes 0..31 reduce 8 partials per s (width-8 groups)
  float bv = -INFINITY; int bi = 0;
  {
    const int ss = (lane >> 3) & 3;
    const int q  = lane & 7;
    if (lane < 32) {
      const float2 p = part[((size_t)token * S_SP + ss) * 8 + q];
      bv = p.x; bi = __float_as_int(p.y);
    }
#pragma unroll
    for (int o = 4; o > 0; o >>= 1) {
      const float ov = __shfl_down(bv, o, 8);
      const int   oi = __shfl_down(bi, o, 8);
      if (ov > bv || (ov == bv && oi < bi)) { bv = ov; bi = oi; }
    }
  }
  int h[4];
#pragma unroll
  for (int s2 = 0; s2 < 4; ++s2)
    h[s2] = s2 * CHUNK + __shfl(bi, s2 * 8);

  const int d0 = lane * 16;
  const float* xp = x + (size_t)token * D_DIM + d0;
  const float4 x0 = *(const float4*)(xp + 0);
  const float4 x1 = *(const float4*)(xp + 4);
  const float4 x2 = *(const float4*)(xp + 8);
  const float4 x3 = *(const float4*)(xp + 12);
  float p[4];
#pragma unroll
  for (int s2 = 0; s2 < 4; ++s2) {
    const float* wr = W1 + (size_t)h[s2] * D_DIM + d0;
    const float4 a0 = *(const float4*)(wr + 0);
    const float4 a1 = *(const float4*)(wr + 4);
    const float4 a2 = *(const float4*)(wr + 8);
    const float4 a3 = *(const float4*)(wr + 12);
    float v = 0.f;
    v = fmaf(x0.x, a0.x, v); v = fmaf(x0.y, a0.y, v);
    v = fmaf(x0.z, a0.z, v); v = fmaf(x0.w, a0.w, v);
    v = fmaf(x1.x, a1.x, v); v = fmaf(x1.y, a1.y, v);
    v = fmaf(x1.z, a1.z, v); v = fmaf(x1.w, a1.w, v);
    v = fmaf(x2.x, a2.x, v); v = fmaf(x2.y, a2.y, v);
    v = fmaf(x2.z, a2.z, v); v = fmaf(x2.w, a2.w, v);
    v = fmaf(x3.x, a3.x, v); v = fmaf(x3.y, a3.y, v);
    v = fmaf(x3.z, a3.z, v); v = fmaf(x3.w, a3.w, v);
    p[s2] = v;
  }
#pragma unroll
  for (int s2 = 0; s2 < 4; ++s2) {
#pragma unroll
    for (int o = 1; o < 64; o <<= 1) p[s2] += __shfl_xor(p[s2], o);
  }
  float hvv[4];
#pragma unroll
  for (int s2 = 0; s2 < 4; ++s2) {
    const float v = p[s2] + b1[h[s2]];
    hvv[s2] = v > 0.f ? v : 0.f;
  }
  float4 o0 = *(const float4*)(b2 + d0 + 0);
  float4 o1 = *(const float4*)(b2 + d0 + 4);
  float4 o2 = *(const float4*)(b2 + d0 + 8);
  float4 o3 = *(const float4*)(b2 + d0 + 12);
#pragma unroll
  for (int s2 = 0; s2 < 4; ++s2) {
    const float* wr = W2T + (size_t)h[s2] * D_DIM + d0;
    const float4 a0 = *(const float4*)(wr + 0);
    const float4 a1 = *(const float4*)(wr + 4);
    const float4 a2 = *(const float4*)(wr + 8);
    const float4 a3 = *(const float4*)(wr + 12);
    const float g = hvv[s2];
    o0.x = fmaf(g, a0.x, o0.x); o0.y = fmaf(g, a0.y, o0.y);
    o0.z = fmaf(g, a0.z, o0.z); o0.w = fmaf(g, a0.w, o0.w);
    o1.x = fmaf(g, a1.x, o1.x); o1.y = fmaf(g, a1.y, o1.y);
    o1.z = fmaf(g, a1.z, o1.z); o1.w = fmaf(g, a1.w, o1.w);
    o2.x = fmaf(g, a2.x, o2.x); o2.y = fmaf(g, a2.y, o2.y);
    o2.z = fmaf(g, a2.z, o2.z); o2.w = fmaf(g, a2.w, o2.w);
    o3.x = fmaf(g, a3.x, o3.x); o3.y = fmaf(g, a3.y, o3.y);
    o3.z = fmaf(g, a3.z, o3.z); o3.w = fmaf(g, a3.w, o3.w);
  }
  float* op = out + (size_t)token * D_DIM + d0;
  *(float4*)(op + 0)  = o0;
  *(float4*)(op + 4)  = o1;
  *(float4*)(op + 8)  = o2;
  *(float4*)(op + 12) = o3;
}

extern "C" void kernel_launch(void* const* d_in, const int* in_sizes, int n_in,
                              void* d_out, int out_size, void* d_ws, size_t ws_size,
                              hipStream_t stream) {
  const float* x      = (const float*)d_in[0];
  const float* W1     = (const float*)d_in[1];
  const float* b1     = (const float*)d_in[2];
  const float* W2     = (const float*)d_in[3];
  const float* b2     = (const float*)d_in[4];
  const float* Wc1    = (const float*)d_in[5];
  const float* bc1    = (const float*)d_in[6];
  const float* Wc2    = (const float*)d_in[7];
  const float* bc2    = (const float*)d_in[8];
  const float* gumbel = (const float*)d_in[9];
  float* out = (float*)d_out;

  char* ws = (char*)d_ws;
  float*  W2T   = (float*)ws;                                   // 16.78 MB
  float*  chT_g = (float*)(ws + 16777216);                      //  2.10 MB
  float2* part  = (float2*)(ws + 16777216 + 2097152);           //  2.10 MB
  float*  Wc2T  = (float*)(ws + 16777216 + 2097152 + 2097152);  //  1.05 MB

  hipLaunchKernelGGL(k_fusedA, dim3(1088 + NTOK / C_TOK), dim3(256), 0, stream,
                     W2, W2T, Wc2, Wc2T, x, Wc1, bc1, chT_g);
  hipLaunchKernelGGL(k_gate_a, dim3(NTOK / G_TOK, CHUNK / G_HB, S_SP), dim3(256), 0, stream,
                     chT_g, Wc2T, bc2, gumbel, part);
  hipLaunchKernelGGL(k_ffn, dim3(NTOK / 4), dim3(256), 0, stream,
                     x, W1, b1, W2T, b2, part, out);
}

// Round 14
// 181.696 us; speedup vs baseline: 1.3975x; 1.2876x over previous
//
#include <hip/hip_runtime.h>
#include <math.h>

#define D_DIM 1024
#define H_DIM 4096
#define R_DIM 64
#define S_SP  4
#define NTOK  8192
#define CHUNK 1024   // H/S

// async global->LDS DMA: wave-uniform LDS base + lane*16 dest, per-lane src
__device__ __forceinline__ void gload_lds16(const float* g, float* l) {
  __builtin_amdgcn_global_load_lds(
      (const __attribute__((address_space(1))) unsigned int*)(unsigned long long)(uintptr_t)g,
      (__attribute__((address_space(3))) unsigned int*)(uintptr_t)l,
      16, 0, 0);
}

// ---- K_A: fused {W2 transpose | Wc2 transpose | ctrl GEMM} ----
#define C_TOK 16
__global__ __launch_bounds__(256, 4) void k_fusedA(const float* __restrict__ W2,
                                                   float* __restrict__ W2T,
                                                   const float* __restrict__ Wc2,
                                                   float* __restrict__ Wc2T,
                                                   const float* __restrict__ x,
                                                   const float* __restrict__ Wc1,
                                                   const float* __restrict__ bc1,
                                                   float* __restrict__ chT_g) {
  __shared__ float smem[64 * 68 + 64 * 20];
  int bid = blockIdx.x;
  const int tid = threadIdx.x;
  if (bid < 1088) {
    float (*tile)[65] = (float (*)[65])smem;
    const float* in; float* out; int R, C, cb, rb;
    if (bid < 1024) {
      in = W2; out = W2T; R = D_DIM; C = H_DIM;
      cb = (bid & 63) * 64; rb = (bid >> 6) * 64;
    } else {
      bid -= 1024;
      in = Wc2; out = Wc2T; R = H_DIM; C = R_DIM;
      cb = 0; rb = bid * 64;
    }
    const int tx = tid & 63, ty = tid >> 6;
#pragma unroll
    for (int r = 0; r < 16; ++r) {
      const int rr = ty * 16 + r;
      tile[tx][rr] = in[(size_t)(rb + rr) * C + cb + tx];
    }
    __syncthreads();
#pragma unroll
    for (int r = 0; r < 16; ++r) {
      const int cc = ty * 16 + r;
      out[(size_t)(cb + cc) * R + rb + tx] = tile[cc][tx];
    }
    return;
  }
  float (*wT)[68] = (float (*)[68])smem;               // [k][r]
  float (*xT)[20] = (float (*)[20])(smem + 64 * 68);   // [k][tok]
  const int tok0 = (bid - 1088) * C_TOK;
  const int lrow = tid >> 4;
  const int lk4  = (tid & 15) * 4;
  const int th = tid & 15;
  const int r4 = (tid >> 4) * 4;
  float acc[4] = {0.f, 0.f, 0.f, 0.f};
#pragma unroll 1
  for (int k0 = 0; k0 < D_DIM; k0 += 64) {
    __syncthreads();
    {
      const float4 v = *(const float4*)(x + (size_t)(tok0 + lrow) * D_DIM + k0 + lk4);
      xT[lk4 + 0][lrow] = v.x; xT[lk4 + 1][lrow] = v.y;
      xT[lk4 + 2][lrow] = v.z; xT[lk4 + 3][lrow] = v.w;
    }
#pragma unroll
    for (int rep = 0; rep < 4; ++rep) {
      const int row = lrow + rep * 16;
      const float4 v = *(const float4*)(Wc1 + (size_t)row * D_DIM + k0 + lk4);
      wT[lk4 + 0][row] = v.x; wT[lk4 + 1][row] = v.y;
      wT[lk4 + 2][row] = v.z; wT[lk4 + 3][row] = v.w;
    }
    __syncthreads();
#pragma unroll 8
    for (int k = 0; k < 64; ++k) {
      const float xv = xT[k][th];
      const float4 wv = *(const float4*)&wT[k][r4];
      acc[0] = fmaf(xv, wv.x, acc[0]);
      acc[1] = fmaf(xv, wv.y, acc[1]);
      acc[2] = fmaf(xv, wv.z, acc[2]);
      acc[3] = fmaf(xv, wv.w, acc[3]);
    }
  }
#pragma unroll
  for (int j = 0; j < 4; ++j) {
    const float v = acc[j] + bc1[r4 + j];
    chT_g[(size_t)(r4 + j) * NTOK + tok0 + th] = v > 0.f ? v : 0.f;
  }
}

// ---- K2a: 128tok x 128h tile, K=64 in two 32-phases, DMA-staged LDS ----
// R8 structure; acc INITIALIZED to bias+gumbel (loads issue pre-GEMM, their
// latency hides under the first staging phase; zero extra registers).
#define G_TOK 128
#define G_HB  128
__global__ __launch_bounds__(256, 4) void k_gate_a(const float* __restrict__ chT_g,
                                                   const float* __restrict__ Wc2T,
                                                   const float* __restrict__ bc2,
                                                   const float* __restrict__ gumbel,
                                                   float2* __restrict__ part) {
  __shared__ float chT[32 * 128];
  __shared__ float wT[32 * 128];
  const int tid = threadIdx.x;
  const int tok0 = blockIdx.x * G_TOK;
  const int hb = blockIdx.y;           // 0..7
  const int s  = blockIdx.z;           // 0..3
  const int h0 = hb * G_HB;
  const int w    = tid >> 6;           // wave 0..3
  const int lane = tid & 63;
  const int lsub = lane >> 5;          // 0/1
  const int lcol = (lane & 31) * 4;
  const int th  = tid & 15;
  const int tt8 = (tid >> 4) * 8;
  const int th4 = th * 4;

  // acc = bias + gumbel  (pre-GEMM; epilogue becomes a pure register scan)
  const float4 b0 = *(const float4*)(bc2 + s * CHUNK + h0 + th4);
  const float4 b1 = *(const float4*)(bc2 + s * CHUNK + h0 + 64 + th4);
  float acc[8][8];
#pragma unroll
  for (int i = 0; i < 8; ++i) {
    const int tok = tok0 + tt8 + i;
    const float* gp = gumbel + ((size_t)tok * S_SP + s) * CHUNK + h0;
    const float4 g0 = *(const float4*)(gp + th4);
    const float4 g1 = *(const float4*)(gp + 64 + th4);
    acc[i][0] = b0.x + g0.x; acc[i][1] = b0.y + g0.y;
    acc[i][2] = b0.z + g0.z; acc[i][3] = b0.w + g0.w;
    acc[i][4] = b1.x + g1.x; acc[i][5] = b1.y + g1.y;
    acc[i][6] = b1.z + g1.z; acc[i][7] = b1.w + g1.w;
  }

#pragma unroll 1
  for (int p = 0; p < 2; ++p) {
    __syncthreads();
#pragma unroll
    for (int j = 0; j < 4; ++j) {
      const int krow = 8 * w + 2 * j + lsub;
      gload_lds16(chT_g + (size_t)(p * 32 + krow) * NTOK + tok0 + lcol,
                  &chT[(8 * w + 2 * j) * 128]);
      gload_lds16(Wc2T + (size_t)(p * 32 + krow) * H_DIM + s * CHUNK + h0 + lcol,
                  &wT[(8 * w + 2 * j) * 128]);
    }
    __syncthreads();
#pragma unroll 8
    for (int k = 0; k < 32; ++k) {
      const float4 c0 = *(const float4*)&chT[k * 128 + tt8];
      const float4 c1 = *(const float4*)&chT[k * 128 + tt8 + 4];
      const float4 w0 = *(const float4*)&wT[k * 128 + th4];
      const float4 w1 = *(const float4*)&wT[k * 128 + 64 + th4];
      const float ca[8] = {c0.x, c0.y, c0.z, c0.w, c1.x, c1.y, c1.z, c1.w};
      const float wa[8] = {w0.x, w0.y, w0.z, w0.w, w1.x, w1.y, w1.z, w1.w};
#pragma unroll
      for (int i = 0; i < 8; ++i)
#pragma unroll
        for (int j = 0; j < 8; ++j) acc[i][j] = fmaf(ca[i], wa[j], acc[i][j]);
    }
  }

  // epilogue: pure register argmax scan (no loads)
#pragma unroll
  for (int i = 0; i < 8; ++i) {
    const int tok = tok0 + tt8 + i;
    float bv = -INFINITY; int bi = 0;
#pragma unroll
    for (int j = 0; j < 8; ++j) {
      const int hl = (j < 4) ? (th4 + j) : (64 + th4 + j - 4);
      const float val = acc[i][j];
      if (val > bv) { bv = val; bi = hl; }   // ascending hl within thread
    }
#pragma unroll
    for (int o = 8; o > 0; o >>= 1) {
      const float ov = __shfl_down(bv, o, 16);
      const int   oi = __shfl_down(bi, o, 16);
      if (ov > bv || (ov == bv && oi < bi)) { bv = ov; bi = oi; }
    }
    if (th == 0)
      part[((size_t)tok * S_SP + s) * 8 + hb] = make_float2(bv, __int_as_float(h0 + bi));
  }
}

// ------- K3: wave-per-token sparse FFN; folds the partial-argmax reduce ---
__global__ __launch_bounds__(256) void k_ffn(const float* __restrict__ x,
                                             const float* __restrict__ W1,
                                             const float* __restrict__ b1,
                                             const float* __restrict__ W2T,
                                             const float* __restrict__ b2,
                                             const float2* __restrict__ part,
                                             float* __restrict__ out) {
  const int tid  = threadIdx.x;
  const int lane = tid & 63;
  const int wv   = tid >> 6;
  const int token = blockIdx.x * 4 + wv;
  // final argmax: lanes 0..31 reduce 8 partials per s (width-8 groups)
  float bv = -INFINITY; int bi = 0;
  {
    const int ss = (lane >> 3) & 3;
    const int q  = lane & 7;
    if (lane < 32) {
      const float2 p = part[((size_t)token * S_SP + ss) * 8 + q];
      bv = p.x; bi = __float_as_int(p.y);
    }
#pragma unroll
    for (int o = 4; o > 0; o >>= 1) {
      const float ov = __shfl_down(bv, o, 8);
      const int   oi = __shfl_down(bi, o, 8);
      if (ov > bv || (ov == bv && oi < bi)) { bv = ov; bi = oi; }
    }
  }
  int h[4];
#pragma unroll
  for (int s2 = 0; s2 < 4; ++s2)
    h[s2] = s2 * CHUNK + __shfl(bi, s2 * 8);

  const int d0 = lane * 16;
  const float* xp = x + (size_t)token * D_DIM + d0;
  const float4 x0 = *(const float4*)(xp + 0);
  const float4 x1 = *(const float4*)(xp + 4);
  const float4 x2 = *(const float4*)(xp + 8);
  const float4 x3 = *(const float4*)(xp + 12);
  float p[4];
#pragma unroll
  for (int s2 = 0; s2 < 4; ++s2) {
    const float* wr = W1 + (size_t)h[s2] * D_DIM + d0;
    const float4 a0 = *(const float4*)(wr + 0);
    const float4 a1 = *(const float4*)(wr + 4);
    const float4 a2 = *(const float4*)(wr + 8);
    const float4 a3 = *(const float4*)(wr + 12);
    float v = 0.f;
    v = fmaf(x0.x, a0.x, v); v = fmaf(x0.y, a0.y, v);
    v = fmaf(x0.z, a0.z, v); v = fmaf(x0.w, a0.w, v);
    v = fmaf(x1.x, a1.x, v); v = fmaf(x1.y, a1.y, v);
    v = fmaf(x1.z, a1.z, v); v = fmaf(x1.w, a1.w, v);
    v = fmaf(x2.x, a2.x, v); v = fmaf(x2.y, a2.y, v);
    v = fmaf(x2.z, a2.z, v); v = fmaf(x2.w, a2.w, v);
    v = fmaf(x3.x, a3.x, v); v = fmaf(x3.y, a3.y, v);
    v = fmaf(x3.z, a3.z, v); v = fmaf(x3.w, a3.w, v);
    p[s2] = v;
  }
#pragma unroll
  for (int s2 = 0; s2 < 4; ++s2) {
#pragma unroll
    for (int o = 1; o < 64; o <<= 1) p[s2] += __shfl_xor(p[s2], o);
  }
  float hvv[4];
#pragma unroll
  for (int s2 = 0; s2 < 4; ++s2) {
    const float v = p[s2] + b1[h[s2]];
    hvv[s2] = v > 0.f ? v : 0.f;
  }
  float4 o0 = *(const float4*)(b2 + d0 + 0);
  float4 o1 = *(const float4*)(b2 + d0 + 4);
  float4 o2 = *(const float4*)(b2 + d0 + 8);
  float4 o3 = *(const float4*)(b2 + d0 + 12);
#pragma unroll
  for (int s2 = 0; s2 < 4; ++s2) {
    const float* wr = W2T + (size_t)h[s2] * D_DIM + d0;
    const float4 a0 = *(const float4*)(wr + 0);
    const float4 a1 = *(const float4*)(wr + 4);
    const float4 a2 = *(const float4*)(wr + 8);
    const float4 a3 = *(const float4*)(wr + 12);
    const float g = hvv[s2];
    o0.x = fmaf(g, a0.x, o0.x); o0.y = fmaf(g, a0.y, o0.y);
    o0.z = fmaf(g, a0.z, o0.z); o0.w = fmaf(g, a0.w, o0.w);
    o1.x = fmaf(g, a1.x, o1.x); o1.y = fmaf(g, a1.y, o1.y);
    o1.z = fmaf(g, a1.z, o1.z); o1.w = fmaf(g, a1.w, o1.w);
    o2.x = fmaf(g, a2.x, o2.x); o2.y = fmaf(g, a2.y, o2.y);
    o2.z = fmaf(g, a2.z, o2.z); o2.w = fmaf(g, a2.w, o2.w);
    o3.x = fmaf(g, a3.x, o3.x); o3.y = fmaf(g, a3.y, o3.y);
    o3.z = fmaf(g, a3.z, o3.z); o3.w = fmaf(g, a3.w, o3.w);
  }
  float* op = out + (size_t)token * D_DIM + d0;
  *(float4*)(op + 0)  = o0;
  *(float4*)(op + 4)  = o1;
  *(float4*)(op + 8)  = o2;
  *(float4*)(op + 12) = o3;
}

extern "C" void kernel_launch(void* const* d_in, const int* in_sizes, int n_in,
                              void* d_out, int out_size, void* d_ws, size_t ws_size,
                              hipStream_t stream) {
  const float* x      = (const float*)d_in[0];
  const float* W1     = (const float*)d_in[1];
  const float* b1     = (const float*)d_in[2];
  const float* W2     = (const float*)d_in[3];
  const float* b2     = (const float*)d_in[4];
  const float* Wc1    = (const float*)d_in[5];
  const float* bc1    = (const float*)d_in[6];
  const float* Wc2    = (const float*)d_in[7];
  const float* bc2    = (const float*)d_in[8];
  const float* gumbel = (const float*)d_in[9];
  float* out = (float*)d_out;

  char* ws = (char*)d_ws;
  float*  W2T   = (float*)ws;                                   // 16.78 MB
  float*  chT_g = (float*)(ws + 16777216);                      //  2.10 MB
  float2* part  = (float2*)(ws + 16777216 + 2097152);           //  2.10 MB
  float*  Wc2T  = (float*)(ws + 16777216 + 2097152 + 2097152);  //  1.05 MB

  hipLaunchKernelGGL(k_fusedA, dim3(1088 + NTOK / C_TOK), dim3(256), 0, stream,
                     W2, W2T, Wc2, Wc2T, x, Wc1, bc1, chT_g);
  hipLaunchKernelGGL(k_gate_a, dim3(NTOK / G_TOK, CHUNK / G_HB, S_SP), dim3(256), 0, stream,
                     chT_g, Wc2T, bc2, gumbel, part);
  hipLaunchKernelGGL(k_ffn, dim3(NTOK / 4), dim3(256), 0, stream,
                     x, W1, b1, W2T, b2, part, out);
}